// Round 6
// baseline (123.329 us; speedup 1.0000x reference)
//
#include <hip/hip_runtime.h>
#include <stdint.h>

typedef __attribute__((ext_vector_type(8))) short short8;
typedef __attribute__((ext_vector_type(4))) float f32x4;

#define MFMA16(A, B, C) __builtin_amdgcn_mfma_f32_16x16x32_bf16(A, B, C, 0, 0, 0)

// fp32 -> bf16 bits, round-to-nearest-even
__device__ __forceinline__ short f2bf(float f) {
    uint32_t u = __float_as_uint(f);
    u = (u + 0x7fffu + ((u >> 16) & 1u)) >> 16;
    return (short)u;
}
__device__ __forceinline__ float bf2f(short s) {
    return __uint_as_float(((uint32_t)(uint16_t)s) << 16);
}
// pack trunc-bf16(a) lo, trunc-bf16(b) hi: 1 v_perm_b32
__device__ __forceinline__ uint32_t pk_bf_trunc(float a, float b) {
    return __builtin_amdgcn_perm(__float_as_uint(b), __float_as_uint(a), 0x07060302u);
}
union PFU { uint32_t u[4]; short8 s; };

// async global->LDS DMA, 16 B/lane (global_load_lds_dwordx4); dest = uniform
// base + lane*16; drained by the s_waitcnt the compiler emits before s_barrier.
__device__ __forceinline__ void async_cp16(void* lds, const void* gm) {
    __builtin_amdgcn_global_load_lds(
        (const __attribute__((address_space(1))) unsigned int*)gm,
        (__attribute__((address_space(3))) unsigned int*)lds,
        16, 0, 0);
}

// XOR-swizzle within a 64x64 short tile (bank-balance for ds_read_b128 while
// the global->LDS image stays an identity copy)
__device__ __forceinline__ int swz(int row, int col) {
    return row * 64 + ((((col >> 3) ^ (row & 7)) << 3) | (col & 7));
}
// PV k-permutation: V value for j stored at column pi(j); matches the register
// order in which P^T exits the S^T MFMA accumulators (see k_attn).
__device__ __forceinline__ int pimap(int j) {
    return ((j >> 5) << 5) + (((j >> 2) & 3) << 3) + (((j >> 4) & 1) << 2) + (j & 3);
}

// load 8 contiguous fp32 from global, convert to bf16x8 fragment
__device__ __forceinline__ short8 ldg_f8_bf(const float* __restrict__ p) {
    float4 a = *(const float4*)p;
    float4 b = *(const float4*)(p + 4);
    short8 r;
    r[0] = f2bf(a.x); r[1] = f2bf(a.y); r[2] = f2bf(a.z); r[3] = f2bf(a.w);
    r[4] = f2bf(b.x); r[5] = f2bf(b.y); r[6] = f2bf(b.z); r[7] = f2bf(b.w);
    return r;
}

// ---------------------------------------------------------------------------
// Kernel 1: fused LayerNorm + q projection (MFMA) + depthwise 3x3 k,v convs.
// Grid (64 rows h, 4 batches), block 512. LN stats from registers; lng/lnb via
// wave-uniform scalar loads; 5 barriers.
// Outputs:
//   Qt[b][i][c] bf16, stride 64, q pre-scaled by log2(e)/8
//   KVg per (b,jt) tile of 8192 shorts:
//     K: element (jl, c)      at swz(jl, c)
//     V: element (c, pi(jl))  at 4096 + swz(c, pi(jl))
// ---------------------------------------------------------------------------
__global__ __launch_bounds__(512, 2) void k_lnqkv(
    const float* __restrict__ xg, const float* __restrict__ lng, const float* __restrict__ lnb,
    const float* __restrict__ wq, const float* __restrict__ bq,
    const float* __restrict__ wkg, const float* __restrict__ bk,
    const float* __restrict__ wvg, const float* __restrict__ bv,
    short* __restrict__ Qt, short* __restrict__ KVg)
{
    const int t    = threadIdx.x;
    const int wv   = t >> 6;      // wave 0..7
    const int lane = t & 63;
    const int l15  = lane & 15;
    const int quad = lane >> 4;
    const int h    = blockIdx.x;
    const int b    = blockIdx.y;
    const int w    = t & 63;      // spatial col owned in P1/P3
    const int g    = t >> 6;

    __shared__ float xl[3 * 64 * 66];   // [dy*64+c][66]
    __shared__ float sfu[3072];         // union: LN partials -> xnt(short s72) -> vt(short s68)
    __shared__ float wkl[576], wvl[576], bkl[64], bvl[64];
    __shared__ float muL[192], rsL[192];

    // P1: batch global loads + register LN partials + weight staging
    float rv[24];
    float s0 = 0.f, s1 = 0.f, s2 = 0.f, q0 = 0.f, q1 = 0.f, q2 = 0.f;
    #pragma unroll
    for (int k = 0; k < 24; ++k) {
        const int dy = k >> 3, c = g + 8 * (k & 7);
        const int hh = h + dy - 1;
        float v = 0.f;
        if (hh >= 0 && hh < 64) v = xg[((b * 64 + c) * 64 + hh) * 64 + w];
        rv[k] = v;
        if (k < 8)       { s0 += v; q0 = fmaf(v, v, q0); }
        else if (k < 16) { s1 += v; q1 = fmaf(v, v, q1); }
        else             { s2 += v; q2 = fmaf(v, v, q2); }
    }
    float lngv[8], lnbv[8];   // wave-uniform -> scalar loads
    #pragma unroll
    for (int j = 0; j < 8; ++j) { lngv[j] = lng[g + 8 * j]; lnbv[j] = lnb[g + 8 * j]; }
    for (int idx = t; idx < 576; idx += 512) { wkl[idx] = wkg[idx]; wvl[idx] = wvg[idx]; }
    if (t < 64) { bkl[t] = bk[t]; bvl[t] = bv[t]; }
    #pragma unroll
    for (int k = 0; k < 24; ++k)
        xl[((k >> 3) * 64 + g + 8 * (k & 7)) * 66 + w] = rv[k];
    sfu[(0 * 8 + g) * 64 + w] = s0; sfu[(1 * 8 + g) * 64 + w] = s1; sfu[(2 * 8 + g) * 64 + w] = s2;
    sfu[1536 + (0 * 8 + g) * 64 + w] = q0; sfu[1536 + (1 * 8 + g) * 64 + w] = q1; sfu[1536 + (2 * 8 + g) * 64 + w] = q2;
    __syncthreads();

    // P2: reduce partials -> mu, rsqrt
    if (t < 192) {
        int dy = t >> 6, ww = t & 63;
        float S = 0.f, SS = 0.f;
        #pragma unroll
        for (int gg = 0; gg < 8; ++gg) {
            S  += sfu[(dy * 8 + gg) * 64 + ww];
            SS += sfu[1536 + (dy * 8 + gg) * 64 + ww];
        }
        float mu  = S * (1.f / 64.f);
        float var = SS * (1.f / 64.f) - mu * mu;
        muL[t] = mu;
        rsL[t] = rsqrtf(var + 1e-5f);
    }
    __syncthreads();

    // P3: normalize from registers; write xl (conv input) + xnt (q A-frags)
    short* xnt = (short*)sfu;
    {
        float mua = muL[w], rsa = rsL[w];
        float mub = muL[64 + w], rsb = rsL[64 + w];
        float muc = muL[128 + w], rsc = rsL[128 + w];
        #pragma unroll
        for (int k = 0; k < 24; ++k) {
            int dy = k >> 3, c = g + 8 * (k & 7);
            int hh = h + dy - 1;
            float mu = (k < 8) ? mua : (k < 16) ? mub : muc;
            float rs = (k < 8) ? rsa : (k < 16) ? rsb : rsc;
            float v = (rv[k] - mu) * rs * lngv[k & 7] + lnbv[k & 7];
            if (hh < 0 || hh >= 64) v = 0.f;
            xl[(dy * 64 + c) * 66 + w] = v;
            if (dy == 1) xnt[w * 72 + c] = f2bf(v);
        }
    }
    __syncthreads();

    // P5: q = xn^T * wq^T via MFMA. 8 waves: wave=(tile 0..3, half 0..1).
    {
        const int tile = wv >> 1, half = wv & 1;
        short8 af[2];
        #pragma unroll
        for (int kc = 0; kc < 2; ++kc)
            af[kc] = *(const short8*)&xnt[(tile * 16 + l15) * 72 + kc * 32 + quad * 8];
        f32x4 acc[2];
        acc[0] = (f32x4){0.f, 0.f, 0.f, 0.f};
        acc[1] = (f32x4){0.f, 0.f, 0.f, 0.f};
        #pragma unroll
        for (int kc = 0; kc < 2; ++kc) {
            #pragma unroll
            for (int ntl = 0; ntl < 2; ++ntl) {
                int nt = half * 2 + ntl;
                short8 bf = ldg_f8_bf(&wq[(nt * 16 + l15) * 64 + kc * 32 + quad * 8]);
                acc[ntl] = MFMA16(af[kc], bf, acc[ntl]);
            }
        }
        const float c1 = 0.18033688011112042f;  // log2(e)/8 folded into q
        #pragma unroll
        for (int ntl = 0; ntl < 2; ++ntl) {
            int o = (half * 2 + ntl) * 16 + l15;
            float bqv = bq[o];
            #pragma unroll
            for (int r = 0; r < 4; ++r) {
                int ww = tile * 16 + quad * 4 + r;
                Qt[((b * 4096 + h * 64 + ww) << 6) + o] = f2bf((acc[ntl][r] + bqv) * c1);
            }
        }
    }
    __syncthreads();  // xnt reads done before vt overwrite

    // P6: depthwise 3x3; float2 row reads (2-way-free banks); vt in pi-order
    short* vt = (short*)sfu;   // stride 68
    {
        int c  = t & 63;
        int w0 = wv << 3;
        float wk9[9], wv9[9];
        #pragma unroll
        for (int q = 0; q < 9; ++q) { wk9[q] = wkl[c * 9 + q]; wv9[q] = wvl[c * 9 + q]; }
        float acck[8], accv[8];
        #pragma unroll
        for (int j = 0; j < 8; ++j) { acck[j] = bkl[c]; accv[j] = bvl[c]; }
        #pragma unroll
        for (int dy = 0; dy < 3; ++dy) {
            const float* row = &xl[(dy * 64 + c) * 66];
            float r[10];
            r[0] = (w0 == 0) ? 0.f : row[w0 - 1];
            #pragma unroll
            for (int j2 = 0; j2 < 4; ++j2) {
                float2 p2 = *(const float2*)&row[w0 + j2 * 2];
                r[1 + j2 * 2] = p2.x; r[2 + j2 * 2] = p2.y;
            }
            r[9] = (w0 == 56) ? 0.f : row[w0 + 8];
            #pragma unroll
            for (int j = 0; j < 8; ++j) {
                acck[j] += wk9[dy * 3] * r[j] + wk9[dy * 3 + 1] * r[j + 1] + wk9[dy * 3 + 2] * r[j + 2];
                accv[j] += wv9[dy * 3] * r[j] + wv9[dy * 3 + 1] * r[j + 1] + wv9[dy * 3 + 2] * r[j + 2];
            }
        }
        long tb = (long)(b * 64 + h) * 8192;
        #pragma unroll
        for (int j = 0; j < 8; ++j)
            KVg[tb + swz(w0 + j, c)] = f2bf(acck[j]);
        #pragma unroll
        for (int j = 0; j < 8; ++j)
            vt[c * 68 + pimap(w0 + j)] = f2bf(accv[j]);
    }
    __syncthreads();

    // P7: V -> global, b64 granules (pi-positions are contiguous in vt)
    {
        long tb = (long)(b * 64 + h) * 8192 + 4096;
        #pragma unroll
        for (int it = 0; it < 2; ++it) {
            int grp = t + it * 512;          // 1024 groups of 4 shorts
            int c = grp >> 4, s0c = (grp & 15) * 4;
            uint2 v = *(const uint2*)&vt[c * 68 + s0c];
            int dst = c * 64 + ((((s0c >> 3) ^ (c & 7)) << 3) | (s0c & 7));
            *(uint2*)&KVg[tb + dst] = v;
        }
    }
}

// ---------------------------------------------------------------------------
// Kernel 2: flash attention, S^T orientation: S^T = MFMA(A=K, B=Q) puts P^T
// registers directly in PV's B-operand layout (with pi k-permutation baked
// into V's storage) -> zero LDS for P. 64 q-rows/wave (rs=4).
// Grid (32 i-tiles of 128, 4 j-parts, 4 batches), block 128 (2 waves).
// KV tiles double-buffered via global_load_lds DMA; one barrier per tile.
// ---------------------------------------------------------------------------
__global__ __launch_bounds__(128, 2) void k_attn(
    const short* __restrict__ Qt, const short* __restrict__ KVg,
    short* __restrict__ Ogb, float* __restrict__ Lg)
{
    const int t    = threadIdx.x;
    const int wv   = t >> 6;
    const int lane = t & 63;
    const int l15  = lane & 15;
    const int quad = lane >> 4;
    const int ti   = blockIdx.x;
    const int jp   = blockIdx.y;
    const int b    = blockIdx.z;
    const int iw   = ti * 128 + wv * 64;   // wave owns 64 query rows

    __shared__ short kvb0[8192];
    __shared__ short kvb1[8192];

    const short* kvg = KVg + ((long)b * 64 + jp * 16) * 8192;

    short8 qf[4][2];   // B-operand: [n=i][k=c]
    #pragma unroll
    for (int rs = 0; rs < 4; ++rs)
        #pragma unroll
        for (int kc = 0; kc < 2; ++kc)
            qf[rs][kc] = *(const short8*)&Qt[((b * 4096 + iw + rs * 16 + l15) << 6) + kc * 32 + quad * 8];

    f32x4 oacc[4][4];  // [rs][cblk]: O^T rows c=quad*4+r, cols i=l15
    #pragma unroll
    for (int rs = 0; rs < 4; ++rs)
        #pragma unroll
        for (int cb = 0; cb < 4; ++cb) oacc[rs][cb] = (f32x4){0.f, 0.f, 0.f, 0.f};
    float Lp[4] = {0.f, 0.f, 0.f, 0.f};

    // prologue: DMA tile 0 -> kvb0
    #pragma unroll
    for (int ii = 0; ii < 8; ++ii)
        async_cp16(kvb0 + (wv * 8 + ii) * 512, kvg + (wv * 8 + ii) * 512 + lane * 8);

    const int xr = l15 & 7;

    #pragma unroll 1
    for (int jt = 0; jt < 16; ++jt) {
        short* cur = (jt & 1) ? kvb1 : kvb0;
        short* nxt = (jt & 1) ? kvb0 : kvb1;
        __syncthreads();   // drains DMA for cur + fences reuse of nxt
        if (jt < 15) {
            const short* gsrc = kvg + (jt + 1) * 8192;
            #pragma unroll
            for (int ii = 0; ii < 8; ++ii)
                async_cp16(nxt + (wv * 8 + ii) * 512, gsrc + (wv * 8 + ii) * 512 + lane * 8);
        }

        // A-operand fragments from swizzled LDS image (K rows=j, V rows=c)
        short8 kf[4][2], vf[4][2];
        #pragma unroll
        for (int mb = 0; mb < 4; ++mb) {
            int rbase = (mb * 16 + l15) * 64;
            #pragma unroll
            for (int kc = 0; kc < 2; ++kc) {
                int cc = ((kc * 4 + quad) ^ xr) << 3;
                kf[mb][kc] = *(const short8*)&cur[rbase + cc];
                vf[mb][kc] = *(const short8*)&cur[4096 + rbase + cc];
            }
        }

        #pragma unroll
        for (int rs = 0; rs < 4; ++rs) {
            f32x4 sacc[4];
            #pragma unroll
            for (int mb = 0; mb < 4; ++mb) sacc[mb] = (f32x4){0.f, 0.f, 0.f, 0.f};
            #pragma unroll
            for (int kc = 0; kc < 2; ++kc)
                #pragma unroll
                for (int mb = 0; mb < 4; ++mb)
                    sacc[mb] = MFMA16(kf[mb][kc], qf[rs][kc], sacc[mb]);  // S^T

            // P^T = exp2(S^T); lane (i=l15, quad) holds j = mb*16+quad*4+r.
            // Pack straight into PV B-frags: pf[kcp] slots = (mb=2kcp|+1, r).
            PFU pf[2];
            #pragma unroll
            for (int mb = 0; mb < 4; ++mb) {
                float p0 = __builtin_amdgcn_exp2f(sacc[mb][0]);
                float p1 = __builtin_amdgcn_exp2f(sacc[mb][1]);
                float p2 = __builtin_amdgcn_exp2f(sacc[mb][2]);
                float p3 = __builtin_amdgcn_exp2f(sacc[mb][3]);
                Lp[rs] += (p0 + p1) + (p2 + p3);
                pf[mb >> 1].u[(mb & 1) * 2 + 0] = pk_bf_trunc(p0, p1);
                pf[mb >> 1].u[(mb & 1) * 2 + 1] = pk_bf_trunc(p2, p3);
            }
            #pragma unroll
            for (int kcp = 0; kcp < 2; ++kcp)
                #pragma unroll
                for (int cb = 0; cb < 4; ++cb)
                    oacc[rs][cb] = MFMA16(vf[cb][kcp], pf[kcp].s, oacc[rs][cb]);
        }
    }

    const int p = b * 4 + jp;
    #pragma unroll
    for (int rs = 0; rs < 4; ++rs) {
        float L = Lp[rs];
        L += __shfl_xor(L, 16);
        L += __shfl_xor(L, 32);
        int i = iw + rs * 16 + l15;
        if (quad == 0) Lg[p * 4096 + i] = L;
        #pragma unroll
        for (int cb = 0; cb < 4; ++cb) {
            uint2 pk;
            pk.x = ((uint32_t)(uint16_t)f2bf(oacc[rs][cb][1]) << 16) | (uint16_t)f2bf(oacc[rs][cb][0]);
            pk.y = ((uint32_t)(uint16_t)f2bf(oacc[rs][cb][3]) << 16) | (uint16_t)f2bf(oacc[rs][cb][2]);
            *(uint2*)&Ogb[((p * 4096 + i) << 6) + cb * 16 + quad * 4] = pk;
        }
    }
}

// ---------------------------------------------------------------------------
// Kernel 3: merge split-j partials + out = wo @ O^T + bo + x.
// Grid (256 i-tiles of 16, 4 batches), block 256.
// ---------------------------------------------------------------------------
__global__ __launch_bounds__(256, 4) void k_out(
    const short* __restrict__ Ogb, const float* __restrict__ Lg,
    const float* __restrict__ wo, const float* __restrict__ bo,
    const float* __restrict__ xg, float* __restrict__ out)
{
    const int t    = threadIdx.x;
    const int wv4  = t >> 6;
    const int lane = t & 63;
    const int l15  = lane & 15;
    const int quad = lane >> 4;
    const int i0   = blockIdx.x * 16;
    const int b    = blockIdx.y;

    float Ls = 0.f;
    #pragma unroll
    for (int jp = 0; jp < 4; ++jp) Ls += Lg[(b * 4 + jp) * 4096 + i0 + l15];
    float invL = 1.0f / Ls;

    short8 af[2];
    #pragma unroll
    for (int kc = 0; kc < 2; ++kc)
        af[kc] = ldg_f8_bf(&wo[(wv4 * 16 + l15) * 64 + kc * 32 + quad * 8]);

    f32x4 acc = (f32x4){0.f, 0.f, 0.f, 0.f};
    #pragma unroll
    for (int kc = 0; kc < 2; ++kc) {
        float bs[8] = {0.f, 0.f, 0.f, 0.f, 0.f, 0.f, 0.f, 0.f};
        #pragma unroll
        for (int jp = 0; jp < 4; ++jp) {
            short8 ov = *(const short8*)&Ogb[(((b * 4 + jp) * 4096 + i0 + l15) << 6) + kc * 32 + quad * 8];
            #pragma unroll
            for (int e = 0; e < 8; ++e) bs[e] += bf2f(ov[e]);
        }
        short8 bfr;
        #pragma unroll
        for (int e = 0; e < 8; ++e) bfr[e] = f2bf(bs[e] * invL);
        acc = MFMA16(af[kc], bfr, acc);
    }
    #pragma unroll
    for (int r = 0; r < 4; ++r) {
        int o = wv4 * 16 + quad * 4 + r;
        long obase = ((long)(b * 64 + o)) << 12;
        out[obase + i0 + l15] = acc[r] + bo[o] + xg[obase + i0 + l15];
    }
}

extern "C" void kernel_launch(void* const* d_in, const int* in_sizes, int n_in,
                              void* d_out, int out_size, void* d_ws, size_t ws_size,
                              hipStream_t stream) {
    (void)in_sizes; (void)n_in; (void)out_size; (void)ws_size;
    const float* x   = (const float*)d_in[0];
    const float* lng = (const float*)d_in[1];
    const float* lnb = (const float*)d_in[2];
    const float* wq  = (const float*)d_in[3];
    const float* bq  = (const float*)d_in[4];
    const float* wk  = (const float*)d_in[5];
    const float* bk  = (const float*)d_in[6];
    const float* wvw = (const float*)d_in[7];
    const float* bv  = (const float*)d_in[8];
    const float* wo  = (const float*)d_in[9];
    const float* bo  = (const float*)d_in[10];
    float* out = (float*)d_out;

    short* Qt  = (short*)d_ws;              // 4*4096*64 bf16  = 2 MB
    short* KVg = Qt + 4 * 4096 * 64;        // 4*64*8192 bf16  = 4 MB
    short* Ogb = KVg + 4 * 64 * 8192;       // 16*4096*64 bf16 = 8 MB
    float* Lg  = (float*)(Ogb + 16 * 4096 * 64);  // 16*4096 f32 = 256 KB

    k_lnqkv<<<dim3(64, 4), 512, 0, stream>>>(x, lng, lnb, wq, bq, wk, bk, wvw, bv, Qt, KVg);
    k_attn<<<dim3(32, 4, 4), 128, 0, stream>>>(Qt, KVg, Ogb, Lg);
    k_out<<<dim3(256, 4), 256, 0, stream>>>(Ogb, Lg, wo, bo, x, out);
}

// Round 7
// 111.704 us; speedup vs baseline: 1.1041x; 1.1041x over previous
//
#include <hip/hip_runtime.h>
#include <stdint.h>

typedef __attribute__((ext_vector_type(8))) short short8;
typedef __attribute__((ext_vector_type(4))) float f32x4;

#define MFMA16(A, B, C) __builtin_amdgcn_mfma_f32_16x16x32_bf16(A, B, C, 0, 0, 0)

// fp32 -> bf16 bits, round-to-nearest-even
__device__ __forceinline__ short f2bf(float f) {
    uint32_t u = __float_as_uint(f);
    u = (u + 0x7fffu + ((u >> 16) & 1u)) >> 16;
    return (short)u;
}
__device__ __forceinline__ float bf2f(short s) {
    return __uint_as_float(((uint32_t)(uint16_t)s) << 16);
}
// pack trunc-bf16(a) lo, trunc-bf16(b) hi: 1 v_perm_b32
__device__ __forceinline__ uint32_t pk_bf_trunc(float a, float b) {
    return __builtin_amdgcn_perm(__float_as_uint(b), __float_as_uint(a), 0x07060302u);
}
union PFU { uint32_t u[4]; short8 s; };

// async global->LDS DMA, 16 B/lane (global_load_lds_dwordx4); dest = uniform
// base + lane*16; drained by the s_waitcnt the compiler emits before s_barrier.
__device__ __forceinline__ void async_cp16(void* lds, const void* gm) {
    __builtin_amdgcn_global_load_lds(
        (const __attribute__((address_space(1))) unsigned int*)gm,
        (__attribute__((address_space(3))) unsigned int*)lds,
        16, 0, 0);
}

// XOR-swizzle within a 64x64 short tile (bank-balance for ds_read_b128 while
// the global->LDS image stays an identity copy)
__device__ __forceinline__ int swz(int row, int col) {
    return row * 64 + ((((col >> 3) ^ (row & 7)) << 3) | (col & 7));
}
// PV k-permutation: V value for j stored at column pi(j); matches the register
// order in which P^T exits the S^T MFMA accumulators (see k_attn).
__device__ __forceinline__ int pimap(int j) {
    return ((j >> 5) << 5) + (((j >> 2) & 3) << 3) + (((j >> 4) & 1) << 2) + (j & 3);
}

// load 8 contiguous fp32 from global, convert to bf16x8 fragment
__device__ __forceinline__ short8 ldg_f8_bf(const float* __restrict__ p) {
    float4 a = *(const float4*)p;
    float4 b = *(const float4*)(p + 4);
    short8 r;
    r[0] = f2bf(a.x); r[1] = f2bf(a.y); r[2] = f2bf(a.z); r[3] = f2bf(a.w);
    r[4] = f2bf(b.x); r[5] = f2bf(b.y); r[6] = f2bf(b.z); r[7] = f2bf(b.w);
    return r;
}

// ---------------------------------------------------------------------------
// Kernel 1: fused LayerNorm + q projection (MFMA) + depthwise 3x3 k,v convs.
// Grid (64 rows h, 4 batches), block 512. LN stats from registers; lng/lnb via
// wave-uniform scalar loads; 5 barriers. (unchanged from R6)
// ---------------------------------------------------------------------------
__global__ __launch_bounds__(512, 2) void k_lnqkv(
    const float* __restrict__ xg, const float* __restrict__ lng, const float* __restrict__ lnb,
    const float* __restrict__ wq, const float* __restrict__ bq,
    const float* __restrict__ wkg, const float* __restrict__ bk,
    const float* __restrict__ wvg, const float* __restrict__ bv,
    short* __restrict__ Qt, short* __restrict__ KVg)
{
    const int t    = threadIdx.x;
    const int wv   = t >> 6;      // wave 0..7
    const int lane = t & 63;
    const int l15  = lane & 15;
    const int quad = lane >> 4;
    const int h    = blockIdx.x;
    const int b    = blockIdx.y;
    const int w    = t & 63;      // spatial col owned in P1/P3
    const int g    = t >> 6;

    __shared__ float xl[3 * 64 * 66];   // [dy*64+c][66]
    __shared__ float sfu[3072];         // union: LN partials -> xnt(short s72) -> vt(short s68)
    __shared__ float wkl[576], wvl[576], bkl[64], bvl[64];
    __shared__ float muL[192], rsL[192];

    // P1: batch global loads + register LN partials + weight staging
    float rv[24];
    float s0 = 0.f, s1 = 0.f, s2 = 0.f, q0 = 0.f, q1 = 0.f, q2 = 0.f;
    #pragma unroll
    for (int k = 0; k < 24; ++k) {
        const int dy = k >> 3, c = g + 8 * (k & 7);
        const int hh = h + dy - 1;
        float v = 0.f;
        if (hh >= 0 && hh < 64) v = xg[((b * 64 + c) * 64 + hh) * 64 + w];
        rv[k] = v;
        if (k < 8)       { s0 += v; q0 = fmaf(v, v, q0); }
        else if (k < 16) { s1 += v; q1 = fmaf(v, v, q1); }
        else             { s2 += v; q2 = fmaf(v, v, q2); }
    }
    float lngv[8], lnbv[8];   // wave-uniform -> scalar loads
    #pragma unroll
    for (int j = 0; j < 8; ++j) { lngv[j] = lng[g + 8 * j]; lnbv[j] = lnb[g + 8 * j]; }
    for (int idx = t; idx < 576; idx += 512) { wkl[idx] = wkg[idx]; wvl[idx] = wvg[idx]; }
    if (t < 64) { bkl[t] = bk[t]; bvl[t] = bv[t]; }
    #pragma unroll
    for (int k = 0; k < 24; ++k)
        xl[((k >> 3) * 64 + g + 8 * (k & 7)) * 66 + w] = rv[k];
    sfu[(0 * 8 + g) * 64 + w] = s0; sfu[(1 * 8 + g) * 64 + w] = s1; sfu[(2 * 8 + g) * 64 + w] = s2;
    sfu[1536 + (0 * 8 + g) * 64 + w] = q0; sfu[1536 + (1 * 8 + g) * 64 + w] = q1; sfu[1536 + (2 * 8 + g) * 64 + w] = q2;
    __syncthreads();

    // P2: reduce partials -> mu, rsqrt
    if (t < 192) {
        int dy = t >> 6, ww = t & 63;
        float S = 0.f, SS = 0.f;
        #pragma unroll
        for (int gg = 0; gg < 8; ++gg) {
            S  += sfu[(dy * 8 + gg) * 64 + ww];
            SS += sfu[1536 + (dy * 8 + gg) * 64 + ww];
        }
        float mu  = S * (1.f / 64.f);
        float var = SS * (1.f / 64.f) - mu * mu;
        muL[t] = mu;
        rsL[t] = rsqrtf(var + 1e-5f);
    }
    __syncthreads();

    // P3: normalize from registers; write xl (conv input) + xnt (q A-frags)
    short* xnt = (short*)sfu;
    {
        float mua = muL[w], rsa = rsL[w];
        float mub = muL[64 + w], rsb = rsL[64 + w];
        float muc = muL[128 + w], rsc = rsL[128 + w];
        #pragma unroll
        for (int k = 0; k < 24; ++k) {
            int dy = k >> 3, c = g + 8 * (k & 7);
            int hh = h + dy - 1;
            float mu = (k < 8) ? mua : (k < 16) ? mub : muc;
            float rs = (k < 8) ? rsa : (k < 16) ? rsb : rsc;
            float v = (rv[k] - mu) * rs * lngv[k & 7] + lnbv[k & 7];
            if (hh < 0 || hh >= 64) v = 0.f;
            xl[(dy * 64 + c) * 66 + w] = v;
            if (dy == 1) xnt[w * 72 + c] = f2bf(v);
        }
    }
    __syncthreads();

    // P5: q = xn^T * wq^T via MFMA. 8 waves: wave=(tile 0..3, half 0..1).
    {
        const int tile = wv >> 1, half = wv & 1;
        short8 af[2];
        #pragma unroll
        for (int kc = 0; kc < 2; ++kc)
            af[kc] = *(const short8*)&xnt[(tile * 16 + l15) * 72 + kc * 32 + quad * 8];
        f32x4 acc[2];
        acc[0] = (f32x4){0.f, 0.f, 0.f, 0.f};
        acc[1] = (f32x4){0.f, 0.f, 0.f, 0.f};
        #pragma unroll
        for (int kc = 0; kc < 2; ++kc) {
            #pragma unroll
            for (int ntl = 0; ntl < 2; ++ntl) {
                int nt = half * 2 + ntl;
                short8 bf = ldg_f8_bf(&wq[(nt * 16 + l15) * 64 + kc * 32 + quad * 8]);
                acc[ntl] = MFMA16(af[kc], bf, acc[ntl]);
            }
        }
        const float c1 = 0.18033688011112042f;  // log2(e)/8 folded into q
        #pragma unroll
        for (int ntl = 0; ntl < 2; ++ntl) {
            int o = (half * 2 + ntl) * 16 + l15;
            float bqv = bq[o];
            #pragma unroll
            for (int r = 0; r < 4; ++r) {
                int ww = tile * 16 + quad * 4 + r;
                Qt[((b * 4096 + h * 64 + ww) << 6) + o] = f2bf((acc[ntl][r] + bqv) * c1);
            }
        }
    }
    __syncthreads();  // xnt reads done before vt overwrite

    // P6: depthwise 3x3; float2 row reads (2-way-free banks); vt in pi-order
    short* vt = (short*)sfu;   // stride 68
    {
        int c  = t & 63;
        int w0 = wv << 3;
        float wk9[9], wv9[9];
        #pragma unroll
        for (int q = 0; q < 9; ++q) { wk9[q] = wkl[c * 9 + q]; wv9[q] = wvl[c * 9 + q]; }
        float acck[8], accv[8];
        #pragma unroll
        for (int j = 0; j < 8; ++j) { acck[j] = bkl[c]; accv[j] = bvl[c]; }
        #pragma unroll
        for (int dy = 0; dy < 3; ++dy) {
            const float* row = &xl[(dy * 64 + c) * 66];
            float r[10];
            r[0] = (w0 == 0) ? 0.f : row[w0 - 1];
            #pragma unroll
            for (int j2 = 0; j2 < 4; ++j2) {
                float2 p2 = *(const float2*)&row[w0 + j2 * 2];
                r[1 + j2 * 2] = p2.x; r[2 + j2 * 2] = p2.y;
            }
            r[9] = (w0 == 56) ? 0.f : row[w0 + 8];
            #pragma unroll
            for (int j = 0; j < 8; ++j) {
                acck[j] += wk9[dy * 3] * r[j] + wk9[dy * 3 + 1] * r[j + 1] + wk9[dy * 3 + 2] * r[j + 2];
                accv[j] += wv9[dy * 3] * r[j] + wv9[dy * 3 + 1] * r[j + 1] + wv9[dy * 3 + 2] * r[j + 2];
            }
        }
        long tb = (long)(b * 64 + h) * 8192;
        #pragma unroll
        for (int j = 0; j < 8; ++j)
            KVg[tb + swz(w0 + j, c)] = f2bf(acck[j]);
        #pragma unroll
        for (int j = 0; j < 8; ++j)
            vt[c * 68 + pimap(w0 + j)] = f2bf(accv[j]);
    }
    __syncthreads();

    // P7: V -> global, b64 granules (pi-positions are contiguous in vt)
    {
        long tb = (long)(b * 64 + h) * 8192 + 4096;
        #pragma unroll
        for (int it = 0; it < 2; ++it) {
            int grp = t + it * 512;          // 1024 groups of 4 shorts
            int c = grp >> 4, s0c = (grp & 15) * 4;
            uint2 v = *(const uint2*)&vt[c * 68 + s0c];
            int dst = c * 64 + ((((s0c >> 3) ^ (c & 7)) << 3) | (s0c & 7));
            *(uint2*)&KVg[tb + dst] = v;
        }
    }
}

// ---------------------------------------------------------------------------
// Kernel 2: flash attention, S^T orientation (P^T exits MFMA directly in PV's
// B-operand layout; pi permutation baked into V storage -> zero LDS for P).
// Grid (64 i-tiles of 64, 4 j-parts, 4 batches), block 128 (2 waves, 32
// q-rows each) -> 2048 waves = 2 waves/SIMD, 4 blocks/CU (R6 lesson: the
// rs=4 variant at 1 wave/SIMD loses more to exposed latency than register
// reuse saves). KV double-buffered via global_load_lds; one barrier/tile.
// ---------------------------------------------------------------------------
__global__ __launch_bounds__(128, 2) void k_attn(
    const short* __restrict__ Qt, const short* __restrict__ KVg,
    short* __restrict__ Ogb, float* __restrict__ Lg)
{
    const int t    = threadIdx.x;
    const int wv   = t >> 6;
    const int lane = t & 63;
    const int l15  = lane & 15;
    const int quad = lane >> 4;
    const int ti   = blockIdx.x;
    const int jp   = blockIdx.y;
    const int b    = blockIdx.z;
    const int iw   = ti * 64 + wv * 32;   // wave owns 32 query rows

    __shared__ short kvb0[8192];
    __shared__ short kvb1[8192];

    const short* kvg = KVg + ((long)b * 64 + jp * 16) * 8192;

    short8 qf[2][2];   // B-operand: [n=i][k=c]
    #pragma unroll
    for (int rs = 0; rs < 2; ++rs)
        #pragma unroll
        for (int kc = 0; kc < 2; ++kc)
            qf[rs][kc] = *(const short8*)&Qt[((b * 4096 + iw + rs * 16 + l15) << 6) + kc * 32 + quad * 8];

    f32x4 oacc[2][4];  // [rs][cblk]: O^T rows c=quad*4+r, cols i=l15
    #pragma unroll
    for (int rs = 0; rs < 2; ++rs)
        #pragma unroll
        for (int cb = 0; cb < 4; ++cb) oacc[rs][cb] = (f32x4){0.f, 0.f, 0.f, 0.f};
    float Lp[2] = {0.f, 0.f};

    // prologue: DMA tile 0 -> kvb0
    #pragma unroll
    for (int ii = 0; ii < 8; ++ii)
        async_cp16(kvb0 + (wv * 8 + ii) * 512, kvg + (wv * 8 + ii) * 512 + lane * 8);

    const int xr = l15 & 7;

    #pragma unroll 1
    for (int jt = 0; jt < 16; ++jt) {
        short* cur = (jt & 1) ? kvb1 : kvb0;
        short* nxt = (jt & 1) ? kvb0 : kvb1;
        __syncthreads();   // drains DMA for cur + fences reuse of nxt
        if (jt < 15) {
            const short* gsrc = kvg + (jt + 1) * 8192;
            #pragma unroll
            for (int ii = 0; ii < 8; ++ii)
                async_cp16(nxt + (wv * 8 + ii) * 512, gsrc + (wv * 8 + ii) * 512 + lane * 8);
        }

        // A-operand fragments from swizzled LDS image (K rows=j, V rows=c)
        short8 kf[4][2], vf[4][2];
        #pragma unroll
        for (int mb = 0; mb < 4; ++mb) {
            int rbase = (mb * 16 + l15) * 64;
            #pragma unroll
            for (int kc = 0; kc < 2; ++kc) {
                int cc = ((kc * 4 + quad) ^ xr) << 3;
                kf[mb][kc] = *(const short8*)&cur[rbase + cc];
                vf[mb][kc] = *(const short8*)&cur[4096 + rbase + cc];
            }
        }

        #pragma unroll
        for (int rs = 0; rs < 2; ++rs) {
            f32x4 sacc[4];
            #pragma unroll
            for (int mb = 0; mb < 4; ++mb) sacc[mb] = (f32x4){0.f, 0.f, 0.f, 0.f};
            #pragma unroll
            for (int kc = 0; kc < 2; ++kc)
                #pragma unroll
                for (int mb = 0; mb < 4; ++mb)
                    sacc[mb] = MFMA16(kf[mb][kc], qf[rs][kc], sacc[mb]);  // S^T

            // P^T = exp2(S^T); lane (i=l15, quad) holds j = mb*16+quad*4+r.
            // Pack straight into PV B-frags: pf[kcp] slots = (mb=2kcp|+1, r).
            PFU pf[2];
            #pragma unroll
            for (int mb = 0; mb < 4; ++mb) {
                float p0 = __builtin_amdgcn_exp2f(sacc[mb][0]);
                float p1 = __builtin_amdgcn_exp2f(sacc[mb][1]);
                float p2 = __builtin_amdgcn_exp2f(sacc[mb][2]);
                float p3 = __builtin_amdgcn_exp2f(sacc[mb][3]);
                Lp[rs] += (p0 + p1) + (p2 + p3);
                pf[mb >> 1].u[(mb & 1) * 2 + 0] = pk_bf_trunc(p0, p1);
                pf[mb >> 1].u[(mb & 1) * 2 + 1] = pk_bf_trunc(p2, p3);
            }
            #pragma unroll
            for (int kcp = 0; kcp < 2; ++kcp)
                #pragma unroll
                for (int cb = 0; cb < 4; ++cb)
                    oacc[rs][cb] = MFMA16(vf[cb][kcp], pf[kcp].s, oacc[rs][cb]);
        }
    }

    const int p = b * 4 + jp;
    #pragma unroll
    for (int rs = 0; rs < 2; ++rs) {
        float L = Lp[rs];
        L += __shfl_xor(L, 16);
        L += __shfl_xor(L, 32);
        int i = iw + rs * 16 + l15;
        if (quad == 0) Lg[p * 4096 + i] = L;
        #pragma unroll
        for (int cb = 0; cb < 4; ++cb) {
            uint2 pk;
            pk.x = ((uint32_t)(uint16_t)f2bf(oacc[rs][cb][1]) << 16) | (uint16_t)f2bf(oacc[rs][cb][0]);
            pk.y = ((uint32_t)(uint16_t)f2bf(oacc[rs][cb][3]) << 16) | (uint16_t)f2bf(oacc[rs][cb][2]);
            *(uint2*)&Ogb[((p * 4096 + i) << 6) + cb * 16 + quad * 4] = pk;
        }
    }
}

// ---------------------------------------------------------------------------
// Kernel 3: merge split-j partials + out = wo @ O^T + bo + x.
// Grid (256 i-tiles of 16, 4 batches), block 256. (unchanged)
// ---------------------------------------------------------------------------
__global__ __launch_bounds__(256, 4) void k_out(
    const short* __restrict__ Ogb, const float* __restrict__ Lg,
    const float* __restrict__ wo, const float* __restrict__ bo,
    const float* __restrict__ xg, float* __restrict__ out)
{
    const int t    = threadIdx.x;
    const int wv4  = t >> 6;
    const int lane = t & 63;
    const int l15  = lane & 15;
    const int quad = lane >> 4;
    const int i0   = blockIdx.x * 16;
    const int b    = blockIdx.y;

    float Ls = 0.f;
    #pragma unroll
    for (int jp = 0; jp < 4; ++jp) Ls += Lg[(b * 4 + jp) * 4096 + i0 + l15];
    float invL = 1.0f / Ls;

    short8 af[2];
    #pragma unroll
    for (int kc = 0; kc < 2; ++kc)
        af[kc] = ldg_f8_bf(&wo[(wv4 * 16 + l15) * 64 + kc * 32 + quad * 8]);

    f32x4 acc = (f32x4){0.f, 0.f, 0.f, 0.f};
    #pragma unroll
    for (int kc = 0; kc < 2; ++kc) {
        float bs[8] = {0.f, 0.f, 0.f, 0.f, 0.f, 0.f, 0.f, 0.f};
        #pragma unroll
        for (int jp = 0; jp < 4; ++jp) {
            short8 ov = *(const short8*)&Ogb[(((b * 4 + jp) * 4096 + i0 + l15) << 6) + kc * 32 + quad * 8];
            #pragma unroll
            for (int e = 0; e < 8; ++e) bs[e] += bf2f(ov[e]);
        }
        short8 bfr;
        #pragma unroll
        for (int e = 0; e < 8; ++e) bfr[e] = f2bf(bs[e] * invL);
        acc = MFMA16(af[kc], bfr, acc);
    }
    #pragma unroll
    for (int r = 0; r < 4; ++r) {
        int o = wv4 * 16 + quad * 4 + r;
        long obase = ((long)(b * 64 + o)) << 12;
        out[obase + i0 + l15] = acc[r] + bo[o] + xg[obase + i0 + l15];
    }
}

extern "C" void kernel_launch(void* const* d_in, const int* in_sizes, int n_in,
                              void* d_out, int out_size, void* d_ws, size_t ws_size,
                              hipStream_t stream) {
    (void)in_sizes; (void)n_in; (void)out_size; (void)ws_size;
    const float* x   = (const float*)d_in[0];
    const float* lng = (const float*)d_in[1];
    const float* lnb = (const float*)d_in[2];
    const float* wq  = (const float*)d_in[3];
    const float* bq  = (const float*)d_in[4];
    const float* wk  = (const float*)d_in[5];
    const float* bk  = (const float*)d_in[6];
    const float* wvw = (const float*)d_in[7];
    const float* bv  = (const float*)d_in[8];
    const float* wo  = (const float*)d_in[9];
    const float* bo  = (const float*)d_in[10];
    float* out = (float*)d_out;

    short* Qt  = (short*)d_ws;              // 4*4096*64 bf16  = 2 MB
    short* KVg = Qt + 4 * 4096 * 64;        // 4*64*8192 bf16  = 4 MB
    short* Ogb = KVg + 4 * 64 * 8192;       // 16*4096*64 bf16 = 8 MB
    float* Lg  = (float*)(Ogb + 16 * 4096 * 64);  // 16*4096 f32 = 256 KB

    k_lnqkv<<<dim3(64, 4), 512, 0, stream>>>(x, lng, lnb, wq, bq, wk, bk, wvw, bv, Qt, KVg);
    k_attn<<<dim3(64, 4, 4), 128, 0, stream>>>(Qt, KVg, Ogb, Lg);
    k_out<<<dim3(256, 4), 256, 0, stream>>>(Ogb, Lg, wo, bo, x, out);
}